// Round 3
// baseline (292.542 us; speedup 1.0000x reference)
//
#include <hip/hip_runtime.h>
#include <stdint.h>

// NCA: B=8, C=16, H=W=128, hidden=128, 8 steps.
// ws: [0,8MB) midA, [8MB,16MB) midB, [+512KB) mid3c, [+128KB) pre,
//     [+2MB) mask bits, [+40KB) f16 split weight fragments. ~18.7 MB.

#define BATCH 8
#define CH 16
#define HT 128
#define WD 128
#define HIDN 128
#define PLANE (HT*WD)
#define IMG (CH*PLANE)
#define NELEM (BATCH*IMG)
#define NPIX (BATCH*PLANE)
#define WORDS_PER_STEP (NELEM/32)
#define NSTEPS 8

// ---- MFMA step kernel geometry (M=32 pixels per wave, 2 A-tiles) ----
// Per-wave LDS region (intra-wave sharing only -> zero barriers):
//   P  (perceived f16 hi/lo): 32 rows x 72 halves x 2B = 4608 B each
//   H  (hidden f16 hi/lo):    32 rows x 136 halves x 2B = 8704 B each
//   DX (fp32 transpose):      32 x 18 x 4B = 2304 B
// Overlays (per-wave DS ops are in-order; lifetimes disjoint):
//   [0,4608) Phi | [4608,9216) Plo | Hhi overlays [0,8704) |
//   [9216,17920) Hlo | DX overlays [0,2304) after GEMM2.
#define PSTR 72      // 144B rows: 16B-aligned b128 A-frag reads, spread banks
#define HSTR 136     // 272B rows: 16B-aligned, near-floor b128 read pattern
#define DSTR 18      // 18-word rows: conflict-free transposed DX reads
#define PLO_OFF 4608
#define HLO_OFF 9216
#define WREG    17920 // x4 waves = 71680 B/block -> 2 blocks/CU

typedef _Float16 f16x8 __attribute__((ext_vector_type(8)));
typedef float    f32x4 __attribute__((ext_vector_type(4)));

struct Keys { unsigned k[2*NSTEPS]; };

__host__ __device__ __forceinline__ unsigned rotl32u(unsigned v, int r) {
  return (v << r) | (v >> (32 - r));
}

// JAX threefry2x32 (20 rounds).
__host__ __device__ __forceinline__ void tf2x32(unsigned k0, unsigned k1,
                                                unsigned c0, unsigned c1,
                                                unsigned &o0, unsigned &o1) {
  const unsigned ks2 = k0 ^ k1 ^ 0x1BD11BDAu;
  unsigned x0 = c0 + k0, x1 = c1 + k1;
  x0 += x1; x1 = rotl32u(x1, 13); x1 ^= x0;
  x0 += x1; x1 = rotl32u(x1, 15); x1 ^= x0;
  x0 += x1; x1 = rotl32u(x1, 26); x1 ^= x0;
  x0 += x1; x1 = rotl32u(x1,  6); x1 ^= x0;
  x0 += k1; x1 += ks2 + 1u;
  x0 += x1; x1 = rotl32u(x1, 17); x1 ^= x0;
  x0 += x1; x1 = rotl32u(x1, 29); x1 ^= x0;
  x0 += x1; x1 = rotl32u(x1, 16); x1 ^= x0;
  x0 += x1; x1 = rotl32u(x1, 24); x1 ^= x0;
  x0 += ks2; x1 += k0 + 2u;
  x0 += x1; x1 = rotl32u(x1, 13); x1 ^= x0;
  x0 += x1; x1 = rotl32u(x1, 15); x1 ^= x0;
  x0 += x1; x1 = rotl32u(x1, 26); x1 ^= x0;
  x0 += x1; x1 = rotl32u(x1,  6); x1 ^= x0;
  x0 += k0; x1 += k1 + 3u;
  x0 += x1; x1 = rotl32u(x1, 17); x1 ^= x0;
  x0 += x1; x1 = rotl32u(x1, 29); x1 ^= x0;
  x0 += x1; x1 = rotl32u(x1, 16); x1 ^= x0;
  x0 += x1; x1 = rotl32u(x1, 24); x1 ^= x0;
  x0 += k1; x1 += ks2 + 4u;
  x0 += x1; x1 = rotl32u(x1, 13); x1 ^= x0;
  x0 += x1; x1 = rotl32u(x1, 15); x1 ^= x0;
  x0 += x1; x1 = rotl32u(x1, 26); x1 ^= x0;
  x0 += x1; x1 = rotl32u(x1,  6); x1 ^= x0;
  x0 += ks2; x1 += k0 + 5u;
  o0 = x0; o1 = x1;
}

// UNCHANGED from baseline: the passing absmax depends on these exact bits.
__global__ __launch_bounds__(256) void mask_kernel(unsigned* __restrict__ mask,
                                                   Keys keys) {
  unsigned t = blockIdx.x * 256u + threadIdx.x;
  unsigned step = t >> 16;
  unsigned k0 = keys.k[2*step], k1 = keys.k[2*step + 1];
  unsigned base = (t & 65535u) << 5;
  unsigned word = 0u;
  #pragma unroll 4
  for (int i = 0; i < 32; ++i) {
    unsigned b1x, b2x;
    tf2x32(k0, k1, 0u, base + (unsigned)i, b1x, b2x);
    unsigned bits = b1x ^ b2x;
    word |= (((bits >> 9) != 0u) ? 1u : 0u) << i;
  }
  mask[t] = word;
}

// UNCHANGED: f16 hi/lo split weights pre-packed in MFMA B-fragment order.
// w1f: [kt(2)][nt(8)][lane(64)][i(8)] halves, k = kt*32+(lane>>4)*8+i
//   (k in [48,64) zero-padded), n = nt*16+(lane&15).
// w2f: [kt(4)][lane(64)][i(8)], k = kt*32+(lane>>4)*8+i, n = lane&15.
__global__ __launch_bounds__(256) void wpack_kernel(
    const float* __restrict__ w1, const float* __restrict__ w2,
    _Float16* __restrict__ w1fh, _Float16* __restrict__ w1fl,
    _Float16* __restrict__ w2fh, _Float16* __restrict__ w2fl) {
  int t = blockIdx.x * 256 + threadIdx.x;   // 10240 threads
  if (t < 8192) {
    int lane = (t >> 3) & 63, i = t & 7;
    int kt = t >> 12, nt = (t >> 9) & 7;
    int k = kt * 32 + (lane >> 4) * 8 + i;
    int n = nt * 16 + (lane & 15);
    float v = (k < 48) ? w1[n * 48 + k] : 0.f;
    _Float16 h = (_Float16)v;
    w1fh[t] = h;
    w1fl[t] = (_Float16)(v - (float)h);
  } else {
    int u = t - 8192;                        // 2048 threads
    int lane = (u >> 3) & 63, i = u & 7;
    int kt = u >> 9;
    int k = kt * 32 + (lane >> 4) * 8 + i;
    int o = lane & 15;
    float v = w2[o * HIDN + k];
    _Float16 h = (_Float16)v;
    w2fh[u] = h;
    w2fl[u] = (_Float16)(v - (float)h);
  }
}

// MFMA step kernel, M=32/wave. 4 waves/block, each wave owns 32 consecutive-x
// pixels (one block = one image row). Per wave: perceive -> split-f16 GEMM1
// (2 A-tiles share every B-fragment: W L2 traffic halves) -> relu/split ->
// GEMM2 -> clamp/mask/residual epilogue. Zero barriers (intra-wave LDS only).
__global__ __launch_bounds__(256, 2) void step_mfma(
    const float* __restrict__ s,
    const f16x8* __restrict__ w1fh, const f16x8* __restrict__ w1fl,
    const f16x8* __restrict__ w2fh, const f16x8* __restrict__ w2fl,
    const float* __restrict__ bias1, const float* __restrict__ bias2,
    const unsigned* __restrict__ mask,
    float* __restrict__ mid,
    float* __restrict__ mid3c,
    unsigned char* __restrict__ pre) {
  __shared__ __align__(16) char smem[4 * WREG];
  const int tid = threadIdx.x;
  const int wv = tid >> 6;
  const int l  = tid & 63;
  const int p  = l & 15;        // MFMA row/col lane index
  const int g  = l >> 4;        // lane group (k-group for A/B frags)
  char* wb = smem + wv * WREG;
  _Float16* Phi = (_Float16*)wb;
  _Float16* Plo = (_Float16*)(wb + PLO_OFF);
  _Float16* Hhi = (_Float16*)wb;            // overlays P (P dead by then)
  _Float16* Hlo = (_Float16*)(wb + HLO_OFF);
  float*    DXl = (float*)wb;               // overlays Hhi (dead after GEMM2)

  const int pid0 = blockIdx.x * 128 + wv * 32;  // wave's first pixel
  const int b  = pid0 >> 14;
  const int r0 = pid0 & 16383;
  const int y  = r0 >> 7;
  const int x0 = r0 & 127;                      // = wv*32
  const bool yu = (y > 0), yd = (y < HT - 1);

  // Early independent loads (overlap with perceive).
  float bv1[8];
  #pragma unroll
  for (int nt = 0; nt < 8; ++nt) bv1[nt] = bias1[nt * 16 + p];
  const float b2v = bias2[p];
  // One mask word covers this wave's 32 pixels (x0..x0+31) per channel.
  unsigned mw[4];
  #pragma unroll
  for (int cc = 0; cc < 4; ++cc)
    mw[cc] = mask[((b * CH + g * 4 + cc) * HT + y) * (WD / 32) + (x0 >> 5)];

  // Zero-pad P feats 48..63 for 32 rows x {hi,lo}: 2 x 16B per lane.
  {
    uint4 z; z.x = 0u; z.y = 0u; z.z = 0u; z.w = 0u;
    *(uint4*)(Phi + (l >> 1) * PSTR + 48 + (l & 1) * 8) = z;
    *(uint4*)(Plo + (l >> 1) * PSTR + 48 + (l & 1) * 8) = z;
  }

  // ---- perceive: lane handles 2 pixels (tiles) x 4 channels ----
  const float* sb = s + b * IMG;
  float sctr[2][4];
  float premax[2] = {-1e30f, -1e30f};
  #pragma unroll
  for (int t = 0; t < 2; ++t) {
    const int xt = x0 + 16 * t + p;
    const int ctr = y * WD + xt;
    const bool xl = (xt > 0), xr = (xt < WD - 1);
    const int row = 16 * t + p;
    #pragma unroll
    for (int cc = 0; cc < 4; ++cc) {
      const int c = g * 4 + cc;
      const float* sc = sb + c * PLANE + ctr;
      float a11 = sc[0];
      float a00 = (yu && xl) ? sc[-WD - 1] : 0.f;
      float a01 = yu         ? sc[-WD]     : 0.f;
      float a02 = (yu && xr) ? sc[-WD + 1] : 0.f;
      float a10 = xl         ? sc[-1]      : 0.f;
      float a12 = xr         ? sc[1]       : 0.f;
      float a20 = (yd && xl) ? sc[WD - 1]  : 0.f;
      float a21 = yd         ? sc[WD]      : 0.f;
      float a22 = (yd && xr) ? sc[WD + 1]  : 0.f;
      float sx = (a02 - a00) + 2.f * (a12 - a10) + (a22 - a20);
      float sy = (a20 - a00) + 2.f * (a21 - a01) + (a22 - a02);
      sctr[t][cc] = a11;
      _Float16 h0 = (_Float16)a11;
      _Float16 h1 = (_Float16)sx;
      _Float16 h2 = (_Float16)sy;
      Phi[row * PSTR + c]      = h0;
      Plo[row * PSTR + c]      = (_Float16)(a11 - (float)h0);
      Phi[row * PSTR + 16 + c] = h1;
      Plo[row * PSTR + 16 + c] = (_Float16)(sx - (float)h1);
      Phi[row * PSTR + 32 + c] = h2;
      Plo[row * PSTR + 32 + c] = (_Float16)(sy - (float)h2);
      if (g == 0 && cc == 3) {   // alive channel: pre-update maxpool
        float m0 = fmaxf(fmaxf(a00, a01), fmaxf(a02, a10));
        float m1 = fmaxf(fmaxf(a11, a12), fmaxf(a20, a21));
        premax[t] = fmaxf(fmaxf(m0, m1), a22);
      }
    }
  }

  asm volatile("" ::: "memory");  // P writes before A-frag reads (same wave)

  // A-fragments for both tiles: row = 16t+p, k = g*8+i.
  f16x8 ah[2][2], al[2][2];
  #pragma unroll
  for (int t = 0; t < 2; ++t) {
    const _Float16* pr = Phi + (16 * t + p) * PSTR;
    const _Float16* lr = Plo + (16 * t + p) * PSTR;
    ah[t][0] = *(const f16x8*)(pr + g * 8);
    ah[t][1] = *(const f16x8*)(pr + 32 + g * 8);
    al[t][0] = *(const f16x8*)(lr + g * 8);
    al[t][1] = *(const f16x8*)(lr + 32 + g * 8);
  }

  // ---- GEMM1: acc[t][nt] = bias1 + P x W1 (split-f16, drop lo*lo).
  // Each B-fragment load feeds BOTH A-tiles -> W L2 traffic halved.
  f32x4 acc[2][8];
  #pragma unroll
  for (int t = 0; t < 2; ++t)
    #pragma unroll
    for (int nt = 0; nt < 8; ++nt) {
      f32x4 a = {bv1[nt], bv1[nt], bv1[nt], bv1[nt]};
      acc[t][nt] = a;
    }
  #pragma unroll
  for (int nt = 0; nt < 8; ++nt) {
    f16x8 bh0 = w1fh[nt * 64 + l];
    f16x8 bh1 = w1fh[512 + nt * 64 + l];
    f16x8 bl0 = w1fl[nt * 64 + l];
    f16x8 bl1 = w1fl[512 + nt * 64 + l];
    #pragma unroll
    for (int t = 0; t < 2; ++t) {
      acc[t][nt] = __builtin_amdgcn_mfma_f32_16x16x32_f16(ah[t][0], bh0, acc[t][nt], 0, 0, 0);
      acc[t][nt] = __builtin_amdgcn_mfma_f32_16x16x32_f16(ah[t][1], bh1, acc[t][nt], 0, 0, 0);
      acc[t][nt] = __builtin_amdgcn_mfma_f32_16x16x32_f16(ah[t][0], bl0, acc[t][nt], 0, 0, 0);
      acc[t][nt] = __builtin_amdgcn_mfma_f32_16x16x32_f16(ah[t][1], bl1, acc[t][nt], 0, 0, 0);
      acc[t][nt] = __builtin_amdgcn_mfma_f32_16x16x32_f16(al[t][0], bh0, acc[t][nt], 0, 0, 0);
      acc[t][nt] = __builtin_amdgcn_mfma_f32_16x16x32_f16(al[t][1], bh1, acc[t][nt], 0, 0, 0);
    }
  }

  // Prefetch GEMM2 B-frags (shared by both tiles).
  f16x8 b2h[4], b2l[4];
  #pragma unroll
  for (int kt = 0; kt < 4; ++kt) {
    b2h[kt] = w2fh[kt * 64 + l];
    b2l[kt] = w2fl[kt * 64 + l];
  }

  // ---- H stage: relu + split into LDS. D layout: row(pixel)=16t+g*4+q,
  // col(hidden)=nt*16+p.
  #pragma unroll
  for (int t = 0; t < 2; ++t)
    #pragma unroll
    for (int nt = 0; nt < 8; ++nt)
      #pragma unroll
      for (int q = 0; q < 4; ++q) {
        float h = fmaxf(acc[t][nt][q], 0.f);
        _Float16 hh = (_Float16)h;
        const int idx = (16 * t + g * 4 + q) * HSTR + nt * 16 + p;
        Hhi[idx] = hh;
        Hlo[idx] = (_Float16)(h - (float)hh);
      }

  asm volatile("" ::: "memory");  // H writes before GEMM2 A-frag reads

  // ---- GEMM2 per tile: dx = bias2 + H x W2; 3 independent 4-MFMA chains.
  f32x4 dx2[2];
  #pragma unroll
  for (int t = 0; t < 2; ++t) {
    f32x4 accP = {b2v, b2v, b2v, b2v};
    f32x4 accQ = {0.f, 0.f, 0.f, 0.f};
    f32x4 accR = {0.f, 0.f, 0.f, 0.f};
    const _Float16* hr = Hhi + (16 * t + p) * HSTR;
    const _Float16* hl = Hlo + (16 * t + p) * HSTR;
    #pragma unroll
    for (int kt = 0; kt < 4; ++kt) {
      f16x8 hA = *(const f16x8*)(hr + kt * 32 + g * 8);
      f16x8 lA = *(const f16x8*)(hl + kt * 32 + g * 8);
      accP = __builtin_amdgcn_mfma_f32_16x16x32_f16(hA, b2h[kt], accP, 0, 0, 0);
      accQ = __builtin_amdgcn_mfma_f32_16x16x32_f16(hA, b2l[kt], accQ, 0, 0, 0);
      accR = __builtin_amdgcn_mfma_f32_16x16x32_f16(lA, b2h[kt], accR, 0, 0, 0);
    }
    dx2[t] = (accP + accQ) + accR;
  }

  // ---- DX transpose through LDS (row=pixel, col=o). DX[0,2304) overlays
  // Hhi rows 0..8 only; all Hhi reads (incl. tile1 rows 16..31) are done.
  #pragma unroll
  for (int t = 0; t < 2; ++t)
    #pragma unroll
    for (int q = 0; q < 4; ++q)
      DXl[(16 * t + g * 4 + q) * DSTR + p] = dx2[t][q];

  asm volatile("" ::: "memory");  // DX writes before reads

  if (g == 0) {
    pre[pid0 + p]      = (premax[0] > 0.1f) ? 1 : 0;
    pre[pid0 + 16 + p] = (premax[1] > 0.1f) ? 1 : 0;
  }

  // ---- epilogue: lane -> (pixel 16t+p, channels 4g..4g+3); residual
  // centers already in registers; coalesced 64B store segments.
  #pragma unroll
  for (int t = 0; t < 2; ++t) {
    const int xt = x0 + 16 * t + p;
    const int rt = y * WD + xt;
    #pragma unroll
    for (int cc = 0; cc < 4; ++cc) {
      const int c = g * 4 + cc;
      float d = DXl[(16 * t + p) * DSTR + c];
      d = fminf(fmaxf(d, -5.f), 5.f);
      float v = sctr[t][cc] + (((mw[cc] >> (16 * t + p)) & 1u) ? d : 0.f);
      mid[b * IMG + c * PLANE + rt] = v;
      if (g == 0 && cc == 3) mid3c[pid0 + 16 * t + p] = v;  // ch3 snapshot
    }
  }
}

// UNCHANGED: post = maxpool3(mid3c) > 0.1; dead pixels zeroed in place.
__global__ __launch_bounds__(256) void fmaskzero_kernel(
    const float* __restrict__ mid3c,
    const unsigned char* __restrict__ pre,
    float* __restrict__ mid) {
  int t = blockIdx.x * 256 + threadIdx.x;   // NPIX
  int b = t >> 14;
  int r = t & 16383;
  int y = r >> 7, x = r & 127;
  const float* m3 = mid3c + b * PLANE;
  float mx = -1e30f;
  #pragma unroll
  for (int dy = -1; dy <= 1; ++dy) {
    int yy = y + dy; if ((unsigned)yy >= HT) continue;
    #pragma unroll
    for (int dxx = -1; dxx <= 1; ++dxx) {
      int xx = x + dxx;
      if ((unsigned)xx < WD) mx = fmaxf(mx, m3[yy * WD + xx]);
    }
  }
  if (!((mx > 0.1f) && pre[t])) {
    float* mp = mid + b * IMG + r;
    #pragma unroll
    for (int c = 0; c < CH; ++c) mp[c * PLANE] = 0.f;
  }
}

// UNCHANGED: final post-alive maxpool + apply pre&post.
__global__ __launch_bounds__(256) void step_b(
    const float* __restrict__ mid,
    const unsigned char* __restrict__ pre,
    float* __restrict__ out) {
  int t = blockIdx.x * 256 + threadIdx.x;   // NPIX threads
  int cq = t >> 15;
  int qid = t & 32767;
  int b = qid >> 12;
  int r = qid & 4095;
  int y = r >> 5;
  int x0 = (r & 31) * 4;
  const float* m3 = mid + b * IMG + 3 * PLANE;

  float col[6];
  #pragma unroll
  for (int j = 0; j < 6; ++j) {
    int xx = x0 - 1 + j;
    float m = -1e30f;
    if ((unsigned)xx < WD) {
      #pragma unroll
      for (int dy = -1; dy <= 1; ++dy) {
        int yy = y + dy;
        if ((unsigned)yy < HT) m = fmaxf(m, m3[yy * WD + xx]);
      }
    }
    col[j] = m;
  }

  const unsigned char* pr = pre + b * PLANE + y * WD + x0;
  float f[4];
  #pragma unroll
  for (int i = 0; i < 4; ++i) {
    float mx = fmaxf(fmaxf(col[i], col[i + 1]), col[i + 2]);
    f[i] = ((mx > 0.1f) && pr[i]) ? 1.f : 0.f;
  }

  #pragma unroll
  for (int cc = 0; cc < 4; ++cc) {
    int c = cq * 4 + cc;
    const float4 v = *(const float4*)&mid[b * IMG + c * PLANE + y * WD + x0];
    float4 w;
    w.x = v.x * f[0]; w.y = v.y * f[1]; w.z = v.z * f[2]; w.w = v.w * f[3];
    *(float4*)&out[b * IMG + c * PLANE + y * WD + x0] = w;
  }
}

extern "C" void kernel_launch(void* const* d_in, const int* in_sizes, int n_in,
                              void* d_out, int out_size, void* d_ws, size_t ws_size,
                              hipStream_t stream) {
  const float* x  = (const float*)d_in[0];
  const float* w1 = (const float*)d_in[1];
  const float* b1 = (const float*)d_in[2];
  const float* w2 = (const float*)d_in[3];
  const float* b2 = (const float*)d_in[4];
  float* out = (float*)d_out;

  char* ws = (char*)d_ws;
  float* midbuf[2];
  midbuf[0] = (float*)ws;
  midbuf[1] = (float*)(ws + (size_t)NELEM * 4);
  float* mid3c = (float*)(ws + 2 * (size_t)NELEM * 4);
  unsigned char* pre = (unsigned char*)(ws + 2 * (size_t)NELEM * 4
                                           + (size_t)NPIX * 4);
  unsigned* mask = (unsigned*)(ws + 2 * (size_t)NELEM * 4
                                  + (size_t)NPIX * 4 + NPIX);
  _Float16* w1fh = (_Float16*)(ws + 2 * (size_t)NELEM * 4 + (size_t)NPIX * 4
                                  + NPIX + (size_t)NSTEPS * WORDS_PER_STEP * 4);
  _Float16* w1fl = w1fh + 8192;
  _Float16* w2fh = w1fl + 8192;
  _Float16* w2fl = w2fh + 2048;

  // keys = jax.random.split(key(42), 8): keys[j] = threefry2x32((0,42),(0,j))
  Keys keys;
  for (int j = 0; j < NSTEPS; ++j) {
    unsigned a, b;
    tf2x32(0u, 42u, 0u, (unsigned)j, a, b);
    keys.k[2 * j] = a; keys.k[2 * j + 1] = b;
  }

  mask_kernel<<<(NSTEPS * WORDS_PER_STEP) / 256, 256, 0, stream>>>(mask, keys);
  wpack_kernel<<<40, 256, 0, stream>>>(w1, w2, w1fh, w1fl, w2fh, w2fl);

  for (int s = 0; s < NSTEPS; ++s) {
    const float* src = (s == 0) ? x : midbuf[(s - 1) & 1];
    step_mfma<<<NPIX / 128, 256, 0, stream>>>(
        src,
        (const f16x8*)w1fh, (const f16x8*)w1fl,
        (const f16x8*)w2fh, (const f16x8*)w2fl,
        b1, b2, mask + s * WORDS_PER_STEP,
        midbuf[s & 1], mid3c, pre);
    if (s < NSTEPS - 1)
      fmaskzero_kernel<<<NPIX / 256, 256, 0, stream>>>(
          mid3c, pre, midbuf[s & 1]);
  }
  step_b<<<NPIX / 256, 256, 0, stream>>>(
      midbuf[(NSTEPS - 1) & 1], pre, out);
}

// Round 4
// 280.498 us; speedup vs baseline: 1.0429x; 1.0429x over previous
//
#include <hip/hip_runtime.h>
#include <stdint.h>

// NCA: B=8, C=16, H=W=128, hidden=128, 8 steps.
// ws: [0,8MB) midA, [8MB,16MB) midB, [+512KB) mid3c, [+128KB) pre,
//     [+2MB) mask bits, [+40KB) f16 split weight fragments. ~18.7 MB.

#define BATCH 8
#define CH 16
#define HT 128
#define WD 128
#define HIDN 128
#define PLANE (HT*WD)
#define IMG (CH*PLANE)
#define NELEM (BATCH*IMG)
#define NPIX (BATCH*PLANE)
#define WORDS_PER_STEP (NELEM/32)
#define NSTEPS 8

// ---- MFMA step kernel geometry (M=32 pixels/wave, 2 tiles, LDS reused) ----
// Per-wave LDS region, tile-sequenced (per-wave DS ops are in-order):
//   P  (perceived f16 hi/lo): 16 rows x 72 halves x 2B = 2304 B each
//   H  (hidden f16 hi/lo):    16 rows x 136 halves x 2B = 4352 B each
// Timeline: pad -> perceive(t0)->A0frags -> perceive(t1) reuses P ->A1frags
//   -> GEMM1 both tiles -> H(t0)->GEMM2(t0) -> H(t1) reuses H ->GEMM2(t1).
// GEMM2 is operand-swapped (D = W2a x Hb) so its D layout matches the
// epilogue lane mapping directly: NO DX transpose region needed.
//   [0,2304) Phi | [2304,4608) Plo | Hhi overlays [0,4352) | [4352,8704) Hlo
#define PSTR 72      // 144B rows: 16B-aligned b128 frag reads, spread banks
#define HSTR 136     // 272B rows: 16B-aligned b128 frag reads
#define PLO_OFF 2304
#define HLO_OFF 4352
#define WREG    8704 // x4 waves = 34816 B/block -> 4 blocks/CU (LDS-wise)

typedef _Float16 f16x8 __attribute__((ext_vector_type(8)));
typedef float    f32x4 __attribute__((ext_vector_type(4)));

struct Keys { unsigned k[2*NSTEPS]; };

__host__ __device__ __forceinline__ unsigned rotl32u(unsigned v, int r) {
  return (v << r) | (v >> (32 - r));
}

// JAX threefry2x32 (20 rounds).
__host__ __device__ __forceinline__ void tf2x32(unsigned k0, unsigned k1,
                                                unsigned c0, unsigned c1,
                                                unsigned &o0, unsigned &o1) {
  const unsigned ks2 = k0 ^ k1 ^ 0x1BD11BDAu;
  unsigned x0 = c0 + k0, x1 = c1 + k1;
  x0 += x1; x1 = rotl32u(x1, 13); x1 ^= x0;
  x0 += x1; x1 = rotl32u(x1, 15); x1 ^= x0;
  x0 += x1; x1 = rotl32u(x1, 26); x1 ^= x0;
  x0 += x1; x1 = rotl32u(x1,  6); x1 ^= x0;
  x0 += k1; x1 += ks2 + 1u;
  x0 += x1; x1 = rotl32u(x1, 17); x1 ^= x0;
  x0 += x1; x1 = rotl32u(x1, 29); x1 ^= x0;
  x0 += x1; x1 = rotl32u(x1, 16); x1 ^= x0;
  x0 += x1; x1 = rotl32u(x1, 24); x1 ^= x0;
  x0 += ks2; x1 += k0 + 2u;
  x0 += x1; x1 = rotl32u(x1, 13); x1 ^= x0;
  x0 += x1; x1 = rotl32u(x1, 15); x1 ^= x0;
  x0 += x1; x1 = rotl32u(x1, 26); x1 ^= x0;
  x0 += x1; x1 = rotl32u(x1,  6); x1 ^= x0;
  x0 += k0; x1 += k1 + 3u;
  x0 += x1; x1 = rotl32u(x1, 17); x1 ^= x0;
  x0 += x1; x1 = rotl32u(x1, 29); x1 ^= x0;
  x0 += x1; x1 = rotl32u(x1, 16); x1 ^= x0;
  x0 += x1; x1 = rotl32u(x1, 24); x1 ^= x0;
  x0 += k1; x1 += ks2 + 4u;
  x0 += x1; x1 = rotl32u(x1, 13); x1 ^= x0;
  x0 += x1; x1 = rotl32u(x1, 15); x1 ^= x0;
  x0 += x1; x1 = rotl32u(x1, 26); x1 ^= x0;
  x0 += x1; x1 = rotl32u(x1,  6); x1 ^= x0;
  x0 += ks2; x1 += k0 + 5u;
  o0 = x0; o1 = x1;
}

// UNCHANGED from baseline: the passing absmax depends on these exact bits.
__global__ __launch_bounds__(256) void mask_kernel(unsigned* __restrict__ mask,
                                                   Keys keys) {
  unsigned t = blockIdx.x * 256u + threadIdx.x;
  unsigned step = t >> 16;
  unsigned k0 = keys.k[2*step], k1 = keys.k[2*step + 1];
  unsigned base = (t & 65535u) << 5;
  unsigned word = 0u;
  #pragma unroll 4
  for (int i = 0; i < 32; ++i) {
    unsigned b1x, b2x;
    tf2x32(k0, k1, 0u, base + (unsigned)i, b1x, b2x);
    unsigned bits = b1x ^ b2x;
    word |= (((bits >> 9) != 0u) ? 1u : 0u) << i;
  }
  mask[t] = word;
}

// UNCHANGED: f16 hi/lo split weights pre-packed in MFMA fragment order.
// w1f (B-frag): [kt(2)][nt(8)][lane(64)][i(8)], k = kt*32+(lane>>4)*8+i
//   (k in [48,64) zero-padded), n = nt*16+(lane&15).
// w2f (A-frag after GEMM2 operand swap — same bytes as the old B-frag):
//   [kt(4)][lane(64)][i(8)], k = kt*32+(lane>>4)*8+i, o = lane&15.
__global__ __launch_bounds__(256) void wpack_kernel(
    const float* __restrict__ w1, const float* __restrict__ w2,
    _Float16* __restrict__ w1fh, _Float16* __restrict__ w1fl,
    _Float16* __restrict__ w2fh, _Float16* __restrict__ w2fl) {
  int t = blockIdx.x * 256 + threadIdx.x;   // 10240 threads
  if (t < 8192) {
    int lane = (t >> 3) & 63, i = t & 7;
    int kt = t >> 12, nt = (t >> 9) & 7;
    int k = kt * 32 + (lane >> 4) * 8 + i;
    int n = nt * 16 + (lane & 15);
    float v = (k < 48) ? w1[n * 48 + k] : 0.f;
    _Float16 h = (_Float16)v;
    w1fh[t] = h;
    w1fl[t] = (_Float16)(v - (float)h);
  } else {
    int u = t - 8192;                        // 2048 threads
    int lane = (u >> 3) & 63, i = u & 7;
    int kt = u >> 9;
    int k = kt * 32 + (lane >> 4) * 8 + i;
    int o = lane & 15;
    float v = w2[o * HIDN + k];
    _Float16 h = (_Float16)v;
    w2fh[u] = h;
    w2fl[u] = (_Float16)(v - (float)h);
  }
}

// MFMA step kernel, M=32/wave with tile-sequenced LDS (8.7 KB/wave).
// 4 waves/block; each wave owns 32 consecutive-x pixels. W fragments are
// loaded once per wave and feed both 16-pixel A-tiles (traffic amortized),
// while the small LDS keeps 3-4 blocks resident/CU for latency hiding.
// Zero barriers: all LDS sharing is intra-wave (DS ops in-order per wave).
__global__ __launch_bounds__(256, 3) void step_mfma(
    const float* __restrict__ s,
    const f16x8* __restrict__ w1fh, const f16x8* __restrict__ w1fl,
    const f16x8* __restrict__ w2fh, const f16x8* __restrict__ w2fl,
    const float* __restrict__ bias1, const float* __restrict__ bias2,
    const unsigned* __restrict__ mask,
    float* __restrict__ mid,
    float* __restrict__ mid3c,
    unsigned char* __restrict__ pre) {
  __shared__ __align__(16) char smem[4 * WREG];
  const int tid = threadIdx.x;
  const int wv = tid >> 6;
  const int l  = tid & 63;
  const int p  = l & 15;        // MFMA row/col lane index
  const int g  = l >> 4;        // lane group (k-group for frags)
  char* wb = smem + wv * WREG;
  _Float16* Phi = (_Float16*)wb;
  _Float16* Plo = (_Float16*)(wb + PLO_OFF);
  _Float16* Hhi = (_Float16*)wb;            // overlays P (P dead by then)
  _Float16* Hlo = (_Float16*)(wb + HLO_OFF);

  const int pid0 = blockIdx.x * 128 + wv * 32;  // wave's first pixel
  const int b  = pid0 >> 14;
  const int r0 = pid0 & 16383;
  const int y  = r0 >> 7;
  const int x0 = r0 & 127;                      // = wv*32
  const bool yu = (y > 0), yd = (y < HT - 1);

  // Early independent loads (overlap with perceive).
  float bv1[8];
  #pragma unroll
  for (int nt = 0; nt < 8; ++nt) bv1[nt] = bias1[nt * 16 + p];
  // Swapped-GEMM2 D: component q holds output-channel o = g*4+q.
  const float4 b2q = *(const float4*)(bias2 + g * 4);
  // One mask word covers this wave's 32 pixels (x0..x0+31) per channel.
  unsigned mw[4];
  #pragma unroll
  for (int cc = 0; cc < 4; ++cc)
    mw[cc] = mask[((b * CH + g * 4 + cc) * HT + y) * (WD / 32) + (x0 >> 5)];

  // Zero-pad P feats 48..63 (16 rows x {hi,lo}): one 16B chunk per lane.
  // Perceive only writes cols 0..47, so the pad survives both tiles.
  {
    uint4 z; z.x = 0u; z.y = 0u; z.z = 0u; z.w = 0u;
    _Float16* zb = (l & 32) ? Plo : Phi;
    *(uint4*)(zb + (l & 15) * PSTR + 48 + ((l >> 4) & 1) * 8) = z;
  }

  // ---- perceive both tiles, tile-sequenced through the SAME P region ----
  const float* sb = s + b * IMG;
  float sctr[2][4];
  float premax[2] = {-1e30f, -1e30f};
  f16x8 ah[2][2], al[2][2];
  #pragma unroll
  for (int t = 0; t < 2; ++t) {
    const int xt = x0 + 16 * t + p;
    const int ctr = y * WD + xt;
    const bool xl = (xt > 0), xr = (xt < WD - 1);
    #pragma unroll
    for (int cc = 0; cc < 4; ++cc) {
      const int c = g * 4 + cc;
      const float* sc = sb + c * PLANE + ctr;
      float a11 = sc[0];
      float a00 = (yu && xl) ? sc[-WD - 1] : 0.f;
      float a01 = yu         ? sc[-WD]     : 0.f;
      float a02 = (yu && xr) ? sc[-WD + 1] : 0.f;
      float a10 = xl         ? sc[-1]      : 0.f;
      float a12 = xr         ? sc[1]       : 0.f;
      float a20 = (yd && xl) ? sc[WD - 1]  : 0.f;
      float a21 = yd         ? sc[WD]      : 0.f;
      float a22 = (yd && xr) ? sc[WD + 1]  : 0.f;
      float sx = (a02 - a00) + 2.f * (a12 - a10) + (a22 - a20);
      float sy = (a20 - a00) + 2.f * (a21 - a01) + (a22 - a02);
      sctr[t][cc] = a11;
      _Float16 h0 = (_Float16)a11;
      _Float16 h1 = (_Float16)sx;
      _Float16 h2 = (_Float16)sy;
      Phi[p * PSTR + c]      = h0;
      Plo[p * PSTR + c]      = (_Float16)(a11 - (float)h0);
      Phi[p * PSTR + 16 + c] = h1;
      Plo[p * PSTR + 16 + c] = (_Float16)(sx - (float)h1);
      Phi[p * PSTR + 32 + c] = h2;
      Plo[p * PSTR + 32 + c] = (_Float16)(sy - (float)h2);
      if (g == 0 && cc == 3) {   // alive channel: pre-update maxpool
        float m0 = fmaxf(fmaxf(a00, a01), fmaxf(a02, a10));
        float m1 = fmaxf(fmaxf(a11, a12), fmaxf(a20, a21));
        premax[t] = fmaxf(fmaxf(m0, m1), a22);
      }
    }
    asm volatile("" ::: "memory");  // P writes before A-frag reads
    const _Float16* pr = Phi + p * PSTR;
    const _Float16* lr = Plo + p * PSTR;
    ah[t][0] = *(const f16x8*)(pr + g * 8);
    ah[t][1] = *(const f16x8*)(pr + 32 + g * 8);
    al[t][0] = *(const f16x8*)(lr + g * 8);
    al[t][1] = *(const f16x8*)(lr + 32 + g * 8);
    asm volatile("" ::: "memory");  // A-frag reads before tile1 P writes
  }

  // ---- GEMM1: acc[t][nt] = bias1 + P x W1 (split-f16, drop lo*lo).
  // Each B-fragment load feeds BOTH A-tiles -> W traffic amortized 2x.
  f32x4 acc[2][8];
  #pragma unroll
  for (int t = 0; t < 2; ++t)
    #pragma unroll
    for (int nt = 0; nt < 8; ++nt) {
      f32x4 a = {bv1[nt], bv1[nt], bv1[nt], bv1[nt]};
      acc[t][nt] = a;
    }
  #pragma unroll
  for (int nt = 0; nt < 8; ++nt) {
    f16x8 bh0 = w1fh[nt * 64 + l];
    f16x8 bh1 = w1fh[512 + nt * 64 + l];
    f16x8 bl0 = w1fl[nt * 64 + l];
    f16x8 bl1 = w1fl[512 + nt * 64 + l];
    #pragma unroll
    for (int t = 0; t < 2; ++t) {
      acc[t][nt] = __builtin_amdgcn_mfma_f32_16x16x32_f16(ah[t][0], bh0, acc[t][nt], 0, 0, 0);
      acc[t][nt] = __builtin_amdgcn_mfma_f32_16x16x32_f16(ah[t][1], bh1, acc[t][nt], 0, 0, 0);
      acc[t][nt] = __builtin_amdgcn_mfma_f32_16x16x32_f16(ah[t][0], bl0, acc[t][nt], 0, 0, 0);
      acc[t][nt] = __builtin_amdgcn_mfma_f32_16x16x32_f16(ah[t][1], bl1, acc[t][nt], 0, 0, 0);
      acc[t][nt] = __builtin_amdgcn_mfma_f32_16x16x32_f16(al[t][0], bh0, acc[t][nt], 0, 0, 0);
      acc[t][nt] = __builtin_amdgcn_mfma_f32_16x16x32_f16(al[t][1], bh1, acc[t][nt], 0, 0, 0);
    }
  }

  // GEMM2 W2 fragments (A-operand of the swapped GEMM2; shared by tiles).
  f16x8 b2h[4], b2l[4];
  #pragma unroll
  for (int kt = 0; kt < 4; ++kt) {
    b2h[kt] = w2fh[kt * 64 + l];
    b2l[kt] = w2fl[kt * 64 + l];
  }

  // ---- H + GEMM2, tile-sequenced through the SAME H region ----
  // Swapped GEMM2: D = W2a x Hb, so D[row=o=g*4+q][col=pixel p] lands in
  // exactly the epilogue's lane mapping (no LDS transpose). Products and
  // k-order are unchanged -> bitwise-identical dx.
  f32x4 dxr[2];
  #pragma unroll
  for (int t = 0; t < 2; ++t) {
    // H layout: row(local pixel)=g*4+q, col(hidden)=nt*16+p.
    #pragma unroll
    for (int nt = 0; nt < 8; ++nt)
      #pragma unroll
      for (int q = 0; q < 4; ++q) {
        float h = fmaxf(acc[t][nt][q], 0.f);
        _Float16 hh = (_Float16)h;
        const int idx = (g * 4 + q) * HSTR + nt * 16 + p;
        Hhi[idx] = hh;
        Hlo[idx] = (_Float16)(h - (float)hh);
      }
    asm volatile("" ::: "memory");  // H writes before B-frag reads
    f32x4 accP = {b2q.x, b2q.y, b2q.z, b2q.w};
    f32x4 accQ = {0.f, 0.f, 0.f, 0.f};
    f32x4 accR = {0.f, 0.f, 0.f, 0.f};
    const _Float16* hr = Hhi + p * HSTR;
    const _Float16* hl = Hlo + p * HSTR;
    #pragma unroll
    for (int kt = 0; kt < 4; ++kt) {
      f16x8 hB = *(const f16x8*)(hr + kt * 32 + g * 8);
      f16x8 lB = *(const f16x8*)(hl + kt * 32 + g * 8);
      accP = __builtin_amdgcn_mfma_f32_16x16x32_f16(b2h[kt], hB, accP, 0, 0, 0);
      accQ = __builtin_amdgcn_mfma_f32_16x16x32_f16(b2l[kt], hB, accQ, 0, 0, 0);
      accR = __builtin_amdgcn_mfma_f32_16x16x32_f16(b2h[kt], lB, accR, 0, 0, 0);
    }
    dxr[t] = (accP + accQ) + accR;
    asm volatile("" ::: "memory");  // B-frag reads before tile1 H writes
  }

  if (g == 0) {
    pre[pid0 + p]      = (premax[0] > 0.1f) ? 1 : 0;
    pre[pid0 + 16 + p] = (premax[1] > 0.1f) ? 1 : 0;
  }

  // ---- epilogue: lane -> (pixel 16t+p, channels 4g..4g+3); dx already in
  // registers (dxr[t][cc]); residual centers in registers; coalesced stores.
  #pragma unroll
  for (int t = 0; t < 2; ++t) {
    const int xt = x0 + 16 * t + p;
    const int rt = y * WD + xt;
    #pragma unroll
    for (int cc = 0; cc < 4; ++cc) {
      const int c = g * 4 + cc;
      float d = dxr[t][cc];
      d = fminf(fmaxf(d, -5.f), 5.f);
      float v = sctr[t][cc] + (((mw[cc] >> (16 * t + p)) & 1u) ? d : 0.f);
      mid[b * IMG + c * PLANE + rt] = v;
      if (g == 0 && cc == 3) mid3c[pid0 + 16 * t + p] = v;  // ch3 snapshot
    }
  }
}

// UNCHANGED: post = maxpool3(mid3c) > 0.1; dead pixels zeroed in place.
__global__ __launch_bounds__(256) void fmaskzero_kernel(
    const float* __restrict__ mid3c,
    const unsigned char* __restrict__ pre,
    float* __restrict__ mid) {
  int t = blockIdx.x * 256 + threadIdx.x;   // NPIX
  int b = t >> 14;
  int r = t & 16383;
  int y = r >> 7, x = r & 127;
  const float* m3 = mid3c + b * PLANE;
  float mx = -1e30f;
  #pragma unroll
  for (int dy = -1; dy <= 1; ++dy) {
    int yy = y + dy; if ((unsigned)yy >= HT) continue;
    #pragma unroll
    for (int dxx = -1; dxx <= 1; ++dxx) {
      int xx = x + dxx;
      if ((unsigned)xx < WD) mx = fmaxf(mx, m3[yy * WD + xx]);
    }
  }
  if (!((mx > 0.1f) && pre[t])) {
    float* mp = mid + b * IMG + r;
    #pragma unroll
    for (int c = 0; c < CH; ++c) mp[c * PLANE] = 0.f;
  }
}

// UNCHANGED: final post-alive maxpool + apply pre&post.
__global__ __launch_bounds__(256) void step_b(
    const float* __restrict__ mid,
    const unsigned char* __restrict__ pre,
    float* __restrict__ out) {
  int t = blockIdx.x * 256 + threadIdx.x;   // NPIX threads
  int cq = t >> 15;
  int qid = t & 32767;
  int b = qid >> 12;
  int r = qid & 4095;
  int y = r >> 5;
  int x0 = (r & 31) * 4;
  const float* m3 = mid + b * IMG + 3 * PLANE;

  float col[6];
  #pragma unroll
  for (int j = 0; j < 6; ++j) {
    int xx = x0 - 1 + j;
    float m = -1e30f;
    if ((unsigned)xx < WD) {
      #pragma unroll
      for (int dy = -1; dy <= 1; ++dy) {
        int yy = y + dy;
        if ((unsigned)yy < HT) m = fmaxf(m, m3[yy * WD + xx]);
      }
    }
    col[j] = m;
  }

  const unsigned char* pr = pre + b * PLANE + y * WD + x0;
  float f[4];
  #pragma unroll
  for (int i = 0; i < 4; ++i) {
    float mx = fmaxf(fmaxf(col[i], col[i + 1]), col[i + 2]);
    f[i] = ((mx > 0.1f) && pr[i]) ? 1.f : 0.f;
  }

  #pragma unroll
  for (int cc = 0; cc < 4; ++cc) {
    int c = cq * 4 + cc;
    const float4 v = *(const float4*)&mid[b * IMG + c * PLANE + y * WD + x0];
    float4 w;
    w.x = v.x * f[0]; w.y = v.y * f[1]; w.z = v.z * f[2]; w.w = v.w * f[3];
    *(float4*)&out[b * IMG + c * PLANE + y * WD + x0] = w;
  }
}

extern "C" void kernel_launch(void* const* d_in, const int* in_sizes, int n_in,
                              void* d_out, int out_size, void* d_ws, size_t ws_size,
                              hipStream_t stream) {
  const float* x  = (const float*)d_in[0];
  const float* w1 = (const float*)d_in[1];
  const float* b1 = (const float*)d_in[2];
  const float* w2 = (const float*)d_in[3];
  const float* b2 = (const float*)d_in[4];
  float* out = (float*)d_out;

  char* ws = (char*)d_ws;
  float* midbuf[2];
  midbuf[0] = (float*)ws;
  midbuf[1] = (float*)(ws + (size_t)NELEM * 4);
  float* mid3c = (float*)(ws + 2 * (size_t)NELEM * 4);
  unsigned char* pre = (unsigned char*)(ws + 2 * (size_t)NELEM * 4
                                           + (size_t)NPIX * 4);
  unsigned* mask = (unsigned*)(ws + 2 * (size_t)NELEM * 4
                                  + (size_t)NPIX * 4 + NPIX);
  _Float16* w1fh = (_Float16*)(ws + 2 * (size_t)NELEM * 4 + (size_t)NPIX * 4
                                  + NPIX + (size_t)NSTEPS * WORDS_PER_STEP * 4);
  _Float16* w1fl = w1fh + 8192;
  _Float16* w2fh = w1fl + 8192;
  _Float16* w2fl = w2fh + 2048;

  // keys = jax.random.split(key(42), 8): keys[j] = threefry2x32((0,42),(0,j))
  Keys keys;
  for (int j = 0; j < NSTEPS; ++j) {
    unsigned a, b;
    tf2x32(0u, 42u, 0u, (unsigned)j, a, b);
    keys.k[2 * j] = a; keys.k[2 * j + 1] = b;
  }

  mask_kernel<<<(NSTEPS * WORDS_PER_STEP) / 256, 256, 0, stream>>>(mask, keys);
  wpack_kernel<<<40, 256, 0, stream>>>(w1, w2, w1fh, w1fl, w2fh, w2fl);

  for (int s = 0; s < NSTEPS; ++s) {
    const float* src = (s == 0) ? x : midbuf[(s - 1) & 1];
    step_mfma<<<NPIX / 128, 256, 0, stream>>>(
        src,
        (const f16x8*)w1fh, (const f16x8*)w1fl,
        (const f16x8*)w2fh, (const f16x8*)w2fl,
        b1, b2, mask + s * WORDS_PER_STEP,
        midbuf[s & 1], mid3c, pre);
    if (s < NSTEPS - 1)
      fmaskzero_kernel<<<NPIX / 256, 256, 0, stream>>>(
          mid3c, pre, midbuf[s & 1]);
  }
  step_b<<<NPIX / 256, 256, 0, stream>>>(
      midbuf[(NSTEPS - 1) & 1], pre, out);
}